// Round 1
// baseline (904.550 us; speedup 1.0000x reference)
//
#include <hip/hip_runtime.h>
#include <math.h>

#define NL 2048
#define N2L 4096

// ============================================================
// K1: r[n][i] = sum_j pos[n][j] * Wr[i][j]   (pos = sinusoid table)
// one 64-thread block per row n
// ============================================================
__global__ void build_r_kernel(const float* __restrict__ Wr, float* __restrict__ r_out) {
  int n = blockIdx.x;
  int t = threadIdx.x;  // 0..63
  __shared__ float pos[64];
  float v = 0.f;
  if (n != 0) {  // padding_idx row zeroed
    int j = t & 31;
    float inv = logf(10000.f) * (1.0f / 31.0f);
    float freq = expf(-inv * (float)j);
    float ang = (float)n * freq;
    v = (t < 32) ? sinf(ang) : cosf(ang);
  }
  pos[t] = v;
  __syncthreads();
  float acc = 0.f;
  const float* wrow = Wr + t * 64;
  #pragma unroll
  for (int j = 0; j < 64; ++j) acc += pos[j] * wrow[j];
  r_out[n * 64 + t] = acc;
}

// ============================================================
// K2: projections.
//  n in [0,512):    qp = q @ Wq^T  -> qA = qp + r_r_bias, qB = qp + r_w_bias
//  n in [512,1024): kh = k @ Wkv[:512]^T
//  n in [1024,1536):vh = k @ Wkv[512:]^T
// outputs in head-major layout [B][H][L][64]
// 64x64 tile, 256 threads, 4x4 micro, K-step 32
// ============================================================
__global__ __launch_bounds__(256) void proj_kernel(
    const float* __restrict__ qin, const float* __restrict__ kin,
    const float* __restrict__ Wq, const float* __restrict__ Wkv,
    const float* __restrict__ rrb, const float* __restrict__ rwb,
    float* __restrict__ qA, float* __restrict__ qB,
    float* __restrict__ khp, float* __restrict__ vhp) {
  __shared__ float AsT[32][68];
  __shared__ float WsT[32][68];
  int tid = threadIdx.x;
  int ty = tid >> 4, tx = tid & 15;
  int m0 = blockIdx.x * 64;
  int n0 = blockIdx.y * 64;
  const float* Amat;
  const float* Wmat;
  if (n0 < 512) { Amat = qin; Wmat = Wq + (size_t)n0 * 512; }
  else          { Amat = kin; Wmat = Wkv + (size_t)(n0 - 512) * 512; }
  float acc[4][4] = {{0.f}};
  for (int c0 = 0; c0 < 512; c0 += 32) {
    __syncthreads();
    #pragma unroll
    for (int rr = 0; rr < 2; ++rr) {
      int fi = tid + 256 * rr;      // 512 float4 = 64 rows x 8
      int m = fi >> 3, c4 = fi & 7;
      float4 av = *reinterpret_cast<const float4*>(&Amat[(size_t)(m0 + m) * 512 + c0 + c4 * 4]);
      AsT[c4*4+0][m] = av.x; AsT[c4*4+1][m] = av.y; AsT[c4*4+2][m] = av.z; AsT[c4*4+3][m] = av.w;
      float4 wv = *reinterpret_cast<const float4*>(&Wmat[(size_t)m * 512 + c0 + c4 * 4]);
      WsT[c4*4+0][m] = wv.x; WsT[c4*4+1][m] = wv.y; WsT[c4*4+2][m] = wv.z; WsT[c4*4+3][m] = wv.w;
    }
    __syncthreads();
    #pragma unroll 8
    for (int c = 0; c < 32; ++c) {
      float4 a = *reinterpret_cast<const float4*>(&AsT[c][ty*4]);
      float4 w = *reinterpret_cast<const float4*>(&WsT[c][tx*4]);
      acc[0][0] += a.x*w.x; acc[0][1] += a.x*w.y; acc[0][2] += a.x*w.z; acc[0][3] += a.x*w.w;
      acc[1][0] += a.y*w.x; acc[1][1] += a.y*w.y; acc[1][2] += a.y*w.z; acc[1][3] += a.y*w.w;
      acc[2][0] += a.z*w.x; acc[2][1] += a.z*w.y; acc[2][2] += a.z*w.z; acc[2][3] += a.z*w.w;
      acc[3][0] += a.w*w.x; acc[3][1] += a.w*w.y; acc[3][2] += a.w*w.z; acc[3][3] += a.w*w.w;
    }
  }
  if (n0 < 512) {
    int h = n0 >> 6;
    float4 rb = *reinterpret_cast<const float4*>(&rrb[n0 + tx*4]);
    float4 rw = *reinterpret_cast<const float4*>(&rwb[n0 + tx*4]);
    #pragma unroll
    for (int i = 0; i < 4; ++i) {
      int m = m0 + ty*4 + i;
      int b = m >> 11, l = m & 2047;
      size_t base = (((size_t)(b*8 + h)) * 2048 + l) * 64 + tx*4;
      *reinterpret_cast<float4*>(&qA[base]) =
          make_float4(acc[i][0]+rb.x, acc[i][1]+rb.y, acc[i][2]+rb.z, acc[i][3]+rb.w);
      *reinterpret_cast<float4*>(&qB[base]) =
          make_float4(acc[i][0]+rw.x, acc[i][1]+rw.y, acc[i][2]+rw.z, acc[i][3]+rw.w);
    }
  } else {
    float* dst = (n0 < 1024) ? khp : vhp;
    int h = ((n0 - 512) >> 6) & 7;
    #pragma unroll
    for (int i = 0; i < 4; ++i) {
      int m = m0 + ty*4 + i;
      int b = m >> 11, l = m & 2047;
      size_t base = (((size_t)(b*8 + h)) * 2048 + l) * 64 + tx*4;
      *reinterpret_cast<float4*>(&dst[base]) = make_float4(acc[i][0], acc[i][1], acc[i][2], acc[i][3]);
    }
  }
}

// ============================================================
// K3: fused attention. One block per (b,h, 32-row q tile), 256 threads.
// S[q,k] = ( qA[q]·kh[k] + qB[q]·r[k-q+L] ) / 8
// phase A: compute S, write raw to attn buffer, online row (m,l) stats
// phase B: re-read raw S, normalize in place, accumulate PV
// ============================================================
__global__ __launch_bounds__(256) void attn_kernel(
    const float* __restrict__ qA, const float* __restrict__ qB,
    const float* __restrict__ kh, const float* __restrict__ vh,
    const float* __restrict__ rtab, const int* __restrict__ mask,
    float* __restrict__ outp, float* __restrict__ attnp) {
  __shared__ float qAsT[64][36];       // [d][rq]
  __shared__ float qBsT[64][36];       // [d][rq]
  __shared__ float sB[64*68];          // phase A: khsT [d][rk]; phase B: vhs [k][d]
  __shared__ float bufC[64*100];       // phase A: rsT [d][j] then Ts [rq][j]; phase B: psT [k][rq]
  __shared__ float m_s[32];
  __shared__ float l_s[32];

  int tid = threadIdx.x;
  int ty = tid >> 4, tx = tid & 15;
  int q0 = blockIdx.x * 32;
  int bh = blockIdx.y;
  int b = bh >> 3;
  int h = bh & 7;
  const float* qAp = qA + (size_t)bh * NL * 64;
  const float* qBp = qB + (size_t)bh * NL * 64;
  const float* khp = kh + (size_t)bh * NL * 64;
  const float* vhp = vh + (size_t)bh * NL * 64;
  float* attn_bh = attnp + (size_t)bh * NL * NL;
  const int* mask_b = mask + (size_t)b * NL * NL;

  #pragma unroll
  for (int rr = 0; rr < 2; ++rr) {
    int fi = tid + 256 * rr;           // 512 = 32 rows * 16 f4
    int rq = fi >> 4, d4 = fi & 15;
    float4 av = *reinterpret_cast<const float4*>(&qAp[(size_t)(q0 + rq) * 64 + d4*4]);
    qAsT[d4*4+0][rq] = av.x; qAsT[d4*4+1][rq] = av.y; qAsT[d4*4+2][rq] = av.z; qAsT[d4*4+3][rq] = av.w;
    float4 bv = *reinterpret_cast<const float4*>(&qBp[(size_t)(q0 + rq) * 64 + d4*4]);
    qBsT[d4*4+0][rq] = bv.x; qBsT[d4*4+1][rq] = bv.y; qBsT[d4*4+2][rq] = bv.z; qBsT[d4*4+3][rq] = bv.w;
  }
  if (tid < 32) { m_s[tid] = -3.0e38f; l_s[tid] = 0.f; }

  // ---------------- phase A ----------------
  for (int kt = 0; kt < 32; ++kt) {
    __syncthreads();
    int k0 = kt * 64;
    int nlo = k0 - q0 + NL - 31;       // r row for j=0 ; j = rk - rq + 31 in [0,94]
    #pragma unroll
    for (int rr = 0; rr < 6; ++rr) {
      int fi = tid + 256 * rr;         // 1536 = 96 rows * 16 f4
      int j = fi >> 4, d4 = fi & 15;
      int n = nlo + j; n = (n > N2L - 1) ? (N2L - 1) : n;  // j=95 unused, clamp
      float4 rv = *reinterpret_cast<const float4*>(&rtab[(size_t)n * 64 + d4*4]);
      bufC[(d4*4+0)*100 + j] = rv.x;
      bufC[(d4*4+1)*100 + j] = rv.y;
      bufC[(d4*4+2)*100 + j] = rv.z;
      bufC[(d4*4+3)*100 + j] = rv.w;
    }
    #pragma unroll
    for (int rr = 0; rr < 4; ++rr) {
      int fi = tid + 256 * rr;         // 1024 = 64 rows * 16 f4
      int kk = fi >> 4, d4 = fi & 15;
      float4 kv = *reinterpret_cast<const float4*>(&khp[(size_t)(k0 + kk) * 64 + d4*4]);
      sB[(d4*4+0)*68 + kk] = kv.x;
      sB[(d4*4+1)*68 + kk] = kv.y;
      sB[(d4*4+2)*68 + kk] = kv.z;
      sB[(d4*4+3)*68 + kk] = kv.w;
    }
    __syncthreads();
    // T-GEMM: T[rq][j] = sum_d qB[rq][d] * r[nlo+j][d]
    float acct[2][6] = {{0.f}};
    #pragma unroll 4
    for (int d = 0; d < 64; ++d) {
      float2 qb = *reinterpret_cast<const float2*>(&qBsT[d][ty*2]);
      const float* rp_ = &bufC[d*100 + tx*6];
      float2 ra = *reinterpret_cast<const float2*>(rp_);
      float2 rb = *reinterpret_cast<const float2*>(rp_ + 2);
      float2 rc = *reinterpret_cast<const float2*>(rp_ + 4);
      acct[0][0] += qb.x * ra.x; acct[1][0] += qb.y * ra.x;
      acct[0][1] += qb.x * ra.y; acct[1][1] += qb.y * ra.y;
      acct[0][2] += qb.x * rb.x; acct[1][2] += qb.y * rb.x;
      acct[0][3] += qb.x * rb.y; acct[1][3] += qb.y * rb.y;
      acct[0][4] += qb.x * rc.x; acct[1][4] += qb.y * rc.x;
      acct[0][5] += qb.x * rc.y; acct[1][5] += qb.y * rc.y;
    }
    __syncthreads();
    #pragma unroll
    for (int i = 0; i < 2; ++i) {      // write Ts over rsT region
      int rq = ty*2 + i;
      #pragma unroll
      for (int jj = 0; jj < 6; ++jj) bufC[rq*100 + tx*6 + jj] = acct[i][jj];
    }
    __syncthreads();
    // AC GEMM: sum_d qA[rq][d] * kh[rk][d]
    float accq[2][4] = {{0.f}};
    #pragma unroll 4
    for (int d = 0; d < 64; ++d) {
      float2 qa = *reinterpret_cast<const float2*>(&qAsT[d][ty*2]);
      float4 kv = *reinterpret_cast<const float4*>(&sB[d*68 + tx*4]);
      accq[0][0] += qa.x * kv.x; accq[1][0] += qa.y * kv.x;
      accq[0][1] += qa.x * kv.y; accq[1][1] += qa.y * kv.y;
      accq[0][2] += qa.x * kv.z; accq[1][2] += qa.y * kv.z;
      accq[0][3] += qa.x * kv.w; accq[1][3] += qa.y * kv.w;
    }
    #pragma unroll
    for (int i = 0; i < 2; ++i) {
      int rq = ty*2 + i;
      int qg = q0 + rq;
      int4 mv = *reinterpret_cast<const int4*>(&mask_b[(size_t)qg * NL + k0 + tx*4]);
      int rk = tx*4;
      float sv0 = (accq[i][0] + bufC[rq*100 + (rk+0) - rq + 31]) * 0.125f;
      float sv1 = (accq[i][1] + bufC[rq*100 + (rk+1) - rq + 31]) * 0.125f;
      float sv2 = (accq[i][2] + bufC[rq*100 + (rk+2) - rq + 31]) * 0.125f;
      float sv3 = (accq[i][3] + bufC[rq*100 + (rk+3) - rq + 31]) * 0.125f;
      if (mv.x == 0) sv0 = -1e30f;
      if (mv.y == 0) sv1 = -1e30f;
      if (mv.z == 0) sv2 = -1e30f;
      if (mv.w == 0) sv3 = -1e30f;
      *reinterpret_cast<float4*>(&attn_bh[(size_t)qg * NL + k0 + tx*4]) = make_float4(sv0, sv1, sv2, sv3);
      float tmax = fmaxf(fmaxf(sv0, sv1), fmaxf(sv2, sv3));
      #pragma unroll
      for (int off = 1; off < 16; off <<= 1) tmax = fmaxf(tmax, __shfl_xor(tmax, off, 16));
      float tsum = __expf(sv0 - tmax) + __expf(sv1 - tmax) + __expf(sv2 - tmax) + __expf(sv3 - tmax);
      #pragma unroll
      for (int off = 1; off < 16; off <<= 1) tsum += __shfl_xor(tsum, off, 16);
      if (tx == 0) {
        float mo = m_s[rq];
        float mn = fmaxf(mo, tmax);
        l_s[rq] = l_s[rq] * __expf(mo - mn) + tsum * __expf(tmax - mn);
        m_s[rq] = mn;
      }
    }
  }
  __syncthreads();
  if (tid < 32) l_s[tid] = 1.0f / l_s[tid];

  // ---------------- phase B ----------------
  float acco[2][4] = {{0.f}};
  for (int kt = 0; kt < 32; ++kt) {
    __syncthreads();
    int k0 = kt * 64;
    #pragma unroll
    for (int rr = 0; rr < 4; ++rr) {   // stage V [k][d]
      int fi = tid + 256 * rr;
      int kk = fi >> 4, d4 = fi & 15;
      float4 vv = *reinterpret_cast<const float4*>(&vhp[(size_t)(k0 + kk) * 64 + d4*4]);
      *reinterpret_cast<float4*>(&sB[kk*68 + d4*4]) = vv;
    }
    #pragma unroll
    for (int i = 0; i < 2; ++i) {
      int rq = ty*2 + i;
      int qg = q0 + rq;
      float4 sv = *reinterpret_cast<const float4*>(&attn_bh[(size_t)qg * NL + k0 + tx*4]);
      float mrow = m_s[rq], rl = l_s[rq];
      float p0 = __expf(sv.x - mrow) * rl;
      float p1 = __expf(sv.y - mrow) * rl;
      float p2 = __expf(sv.z - mrow) * rl;
      float p3 = __expf(sv.w - mrow) * rl;
      *reinterpret_cast<float4*>(&attn_bh[(size_t)qg * NL + k0 + tx*4]) = make_float4(p0, p1, p2, p3);
      bufC[(tx*4+0)*36 + rq] = p0;     // psT [k][rq]
      bufC[(tx*4+1)*36 + rq] = p1;
      bufC[(tx*4+2)*36 + rq] = p2;
      bufC[(tx*4+3)*36 + rq] = p3;
    }
    __syncthreads();
    #pragma unroll 4
    for (int kk = 0; kk < 64; ++kk) {
      float2 pp = *reinterpret_cast<const float2*>(&bufC[kk*36 + ty*2]);
      float4 vv = *reinterpret_cast<const float4*>(&sB[kk*68 + tx*4]);
      acco[0][0] += pp.x * vv.x; acco[1][0] += pp.y * vv.x;
      acco[0][1] += pp.x * vv.y; acco[1][1] += pp.y * vv.y;
      acco[0][2] += pp.x * vv.z; acco[1][2] += pp.y * vv.z;
      acco[0][3] += pp.x * vv.w; acco[1][3] += pp.y * vv.w;
    }
  }
  #pragma unroll
  for (int i = 0; i < 2; ++i) {
    int qg = q0 + ty*2 + i;
    *reinterpret_cast<float4*>(&outp[((size_t)b * NL + qg) * 512 + h*64 + tx*4]) =
        make_float4(acco[i][0], acco[i][1], acco[i][2], acco[i][3]);
  }
}

// ============================================================
extern "C" void kernel_launch(void* const* d_in, const int* in_sizes, int n_in,
                              void* d_out, int out_size, void* d_ws, size_t ws_size,
                              hipStream_t stream) {
  const float* q    = (const float*)d_in[0];
  const float* k    = (const float*)d_in[1];
  const int*   mask = (const int*)d_in[2];
  const float* Wq   = (const float*)d_in[3];
  const float* Wkv  = (const float*)d_in[4];
  const float* Wr   = (const float*)d_in[5];
  const float* rrb  = (const float*)d_in[6];
  const float* rwb  = (const float*)d_in[7];

  float* outp  = (float*)d_out;                       // [2,2048,512]
  float* attnp = outp + (size_t)2 * NL * 512;         // [2,8,2048,2048]

  float* ws   = (float*)d_ws;
  float* rbuf = ws;                                   // [4096][64]
  float* qA   = ws + 262144;                          // [2][8][2048][64]
  float* qB   = qA + 2097152;
  float* khb  = qB + 2097152;
  float* vhb  = khb + 2097152;

  hipLaunchKernelGGL(build_r_kernel, dim3(N2L), dim3(64), 0, stream, Wr, rbuf);
  hipLaunchKernelGGL(proj_kernel, dim3(64, 24), dim3(256), 0, stream,
                     q, k, Wq, Wkv, rrb, rwb, qA, qB, khb, vhb);
  hipLaunchKernelGGL(attn_kernel, dim3(64, 16), dim3(256), 0, stream,
                     qA, qB, khb, vhb, rbuf, mask, outp, attnp);
}

// Round 3
// 667.317 us; speedup vs baseline: 1.3555x; 1.3555x over previous
//
#include <hip/hip_runtime.h>
#include <math.h>

#define NL 2048
#define N2L 4096

typedef __attribute__((ext_vector_type(8))) short bf16x8;
typedef __attribute__((ext_vector_type(4))) float f32x4;
#define MFMA(a,b,c) __builtin_amdgcn_mfma_f32_16x16x32_bf16((a),(b),(c),0,0,0)

__device__ __forceinline__ unsigned short bf16_rne(float x){
  unsigned int u = __float_as_uint(x);
  u += 0x7FFFu + ((u>>16)&1u);
  return (unsigned short)(u>>16);
}
__device__ __forceinline__ float bf16_to_f(unsigned short h){
  return __uint_as_float(((unsigned int)h)<<16);
}

// ============================================================
// K0: split f32 inputs (q, k, Wq, Wkv) into hi/lo bf16 pairs.
// ============================================================
__global__ __launch_bounds__(256) void split_kernel(
    const float* __restrict__ q, const float* __restrict__ k,
    const float* __restrict__ Wq, const float* __restrict__ Wkv,
    unsigned short* __restrict__ qsh, unsigned short* __restrict__ qsl,
    unsigned short* __restrict__ ksh, unsigned short* __restrict__ ksl,
    unsigned short* __restrict__ wqh, unsigned short* __restrict__ wql,
    unsigned short* __restrict__ wkh, unsigned short* __restrict__ wkl) {
  const int C1 = 524288, C2 = 1048576, C3 = 1114112, C4 = 1245184;  // float4 counts
  for (int i = blockIdx.x * blockDim.x + threadIdx.x; i < C4; i += gridDim.x * blockDim.x) {
    const float* src; unsigned short *dh, *dl; int j;
    if (i < C1)      { src = q;   dh = qsh; dl = qsl; j = i; }
    else if (i < C2) { src = k;   dh = ksh; dl = ksl; j = i - C1; }
    else if (i < C3) { src = Wq;  dh = wqh; dl = wql; j = i - C2; }
    else             { src = Wkv; dh = wkh; dl = wkl; j = i - C3; }
    float4 v = reinterpret_cast<const float4*>(src)[j];
    unsigned short h0 = bf16_rne(v.x), h1 = bf16_rne(v.y), h2 = bf16_rne(v.z), h3 = bf16_rne(v.w);
    unsigned short l0 = bf16_rne(v.x - bf16_to_f(h0));
    unsigned short l1 = bf16_rne(v.y - bf16_to_f(h1));
    unsigned short l2 = bf16_rne(v.z - bf16_to_f(h2));
    unsigned short l3 = bf16_rne(v.w - bf16_to_f(h3));
    reinterpret_cast<uint2*>(dh)[j] = make_uint2((unsigned)h0 | ((unsigned)h1 << 16),
                                                 (unsigned)h2 | ((unsigned)h3 << 16));
    reinterpret_cast<uint2*>(dl)[j] = make_uint2((unsigned)l0 | ((unsigned)l1 << 16),
                                                 (unsigned)l2 | ((unsigned)l3 << 16));
  }
}

// ============================================================
// K1: r = sinusoid_table @ Wr^T, stored as hi/lo bf16 [4096][64]
// ============================================================
__global__ void build_r_kernel(const float* __restrict__ Wr,
                               unsigned short* __restrict__ rh,
                               unsigned short* __restrict__ rl) {
  int n = blockIdx.x;
  int t = threadIdx.x;  // 0..63
  __shared__ float pos[64];
  float v = 0.f;
  if (n != 0) {
    int j = t & 31;
    float inv = logf(10000.f) * (1.0f / 31.0f);
    float freq = expf(-inv * (float)j);
    float ang = (float)n * freq;
    v = (t < 32) ? sinf(ang) : cosf(ang);
  }
  pos[t] = v;
  __syncthreads();
  float acc = 0.f;
  const float* wrow = Wr + t * 64;
  #pragma unroll
  for (int j = 0; j < 64; ++j) acc += pos[j] * wrow[j];
  unsigned short hh = bf16_rne(acc);
  rh[n * 64 + t] = hh;
  rl[n * 64 + t] = bf16_rne(acc - bf16_to_f(hh));
}

// ============================================================
// K2: MFMA projections, 3-product split precision.
// by<16 (mode A): D[token][feat] = X @ W^T  -> qA/qB (with bias) or kh
// by>=16 (mode B): D'[feat][token] = Wv @ k^T -> vT (transposed V)
// Block 256 thr = 4 waves; 64x64 tile, K=512.
// ============================================================
__global__ __launch_bounds__(256) void proj_kernel(
    const unsigned short* __restrict__ qsh, const unsigned short* __restrict__ qsl,
    const unsigned short* __restrict__ ksh, const unsigned short* __restrict__ ksl,
    const unsigned short* __restrict__ wqh, const unsigned short* __restrict__ wql,
    const unsigned short* __restrict__ wkh, const unsigned short* __restrict__ wkl,
    const float* __restrict__ rrb, const float* __restrict__ rwb,
    unsigned short* __restrict__ qAh, unsigned short* __restrict__ qAl,
    unsigned short* __restrict__ qBh, unsigned short* __restrict__ qBl,
    unsigned short* __restrict__ khh, unsigned short* __restrict__ khl,
    unsigned short* __restrict__ vTh, unsigned short* __restrict__ vTl) {
  int tid = threadIdx.x;
  int w = tid >> 6, lane = tid & 63, li = lane & 15, g = lane >> 4;
  int bx = blockIdx.x, by = blockIdx.y;
  f32x4 acc[4];
  #pragma unroll
  for (int i = 0; i < 4; ++i) { acc[i][0]=0.f; acc[i][1]=0.f; acc[i][2]=0.f; acc[i][3]=0.f; }

  if (by < 16) {
    int n0 = by * 64, m0 = bx * 64;
    const unsigned short* Xh = (n0 < 512) ? qsh : ksh;
    const unsigned short* Xl = (n0 < 512) ? qsl : ksl;
    const unsigned short* Wh = (n0 < 512) ? (wqh + (size_t)n0 * 512) : (wkh + (size_t)(n0 - 512) * 512);
    const unsigned short* Wl = (n0 < 512) ? (wql + (size_t)n0 * 512) : (wkl + (size_t)(n0 - 512) * 512);
    int rowm = m0 + 16 * w + li;
    for (int ks = 0; ks < 16; ++ks) {
      int d0 = ks * 32 + 8 * g;
      bf16x8 ah = *(const bf16x8*)(Xh + (size_t)rowm * 512 + d0);
      bf16x8 al = *(const bf16x8*)(Xl + (size_t)rowm * 512 + d0);
      #pragma unroll
      for (int nt = 0; nt < 4; ++nt) {
        bf16x8 bh_ = *(const bf16x8*)(Wh + (size_t)(16 * nt + li) * 512 + d0);
        bf16x8 bl_ = *(const bf16x8*)(Wl + (size_t)(16 * nt + li) * 512 + d0);
        acc[nt] = MFMA(ah, bh_, acc[nt]);
        acc[nt] = MFMA(al, bh_, acc[nt]);
        acc[nt] = MFMA(ah, bl_, acc[nt]);
      }
    }
    if (n0 < 512) {
      int h = n0 >> 6;
      #pragma unroll
      for (int nt = 0; nt < 4; ++nt) {
        int d = 16 * nt + li;
        float rrv = rrb[h * 64 + d], rwv = rwb[h * 64 + d];
        #pragma unroll
        for (int r = 0; r < 4; ++r) {
          int m = m0 + 16 * w + 4 * g + r;
          int b = m >> 11, lt = m & 2047;
          size_t base = (((size_t)(b * 8 + h)) * 2048 + lt) * 64 + d;
          float a1 = acc[nt][r] + rrv;
          unsigned short h1 = bf16_rne(a1);
          qAh[base] = h1; qAl[base] = bf16_rne(a1 - bf16_to_f(h1));
          float a2 = acc[nt][r] + rwv;
          unsigned short h2 = bf16_rne(a2);
          qBh[base] = h2; qBl[base] = bf16_rne(a2 - bf16_to_f(h2));
        }
      }
    } else {
      int h = (n0 - 512) >> 6;
      #pragma unroll
      for (int nt = 0; nt < 4; ++nt) {
        int d = 16 * nt + li;
        #pragma unroll
        for (int r = 0; r < 4; ++r) {
          int m = m0 + 16 * w + 4 * g + r;
          int b = m >> 11, lt = m & 2047;
          size_t base = (((size_t)(b * 8 + h)) * 2048 + lt) * 64 + d;
          unsigned short h1 = bf16_rne(acc[nt][r]);
          khh[base] = h1; khl[base] = bf16_rne(acc[nt][r] - bf16_to_f(h1));
        }
      }
    }
  } else {
    // mode B: vT[feat][token]
    int fy = by - 16, m0 = bx * 64, f0 = fy * 64;
    const unsigned short* Ah = wkh + (size_t)(512 + f0 + 16 * w + li) * 512;
    const unsigned short* Al = wkl + (size_t)(512 + f0 + 16 * w + li) * 512;
    for (int ks = 0; ks < 16; ++ks) {
      int d0 = ks * 32 + 8 * g;
      bf16x8 ah = *(const bf16x8*)(Ah + d0);
      bf16x8 al = *(const bf16x8*)(Al + d0);
      #pragma unroll
      for (int nt = 0; nt < 4; ++nt) {
        bf16x8 bh_ = *(const bf16x8*)(ksh + (size_t)(m0 + 16 * nt + li) * 512 + d0);
        bf16x8 bl_ = *(const bf16x8*)(ksl + (size_t)(m0 + 16 * nt + li) * 512 + d0);
        acc[nt] = MFMA(ah, bh_, acc[nt]);
        acc[nt] = MFMA(al, bh_, acc[nt]);
        acc[nt] = MFMA(ah, bl_, acc[nt]);
      }
    }
    int h = fy;
    #pragma unroll
    for (int nt = 0; nt < 4; ++nt) {
      int m = m0 + 16 * nt + li;
      int b = m >> 11, lt = m & 2047;
      #pragma unroll
      for (int r = 0; r < 4; ++r) {
        int d = 16 * w + 4 * g + r;
        size_t base = (((size_t)(b * 8 + h)) * 64 + d) * 2048 + lt;
        unsigned short h1 = bf16_rne(acc[nt][r]);
        vTh[base] = h1; vTl[base] = bf16_rne(acc[nt][r] - bf16_to_f(h1));
      }
    }
  }
}

// ============================================================
// K3: fused attention. Block = (32 q rows) x (b,h); 256 thr = 4 waves.
// Phase A: S^T = K·qA^T + gather(T=r·qB^T), raw S -> attn buffer, online m/l.
// Phase B: re-read S, p=exp(S-m)/l -> attn buffer, PV via out^T = V^T·P^T.
// ============================================================
__global__ __launch_bounds__(256) void attn_kernel(
    const unsigned short* __restrict__ qAh, const unsigned short* __restrict__ qAl,
    const unsigned short* __restrict__ qBh, const unsigned short* __restrict__ qBl,
    const unsigned short* __restrict__ khh, const unsigned short* __restrict__ khl,
    const unsigned short* __restrict__ vTh, const unsigned short* __restrict__ vTl,
    const unsigned short* __restrict__ rh, const unsigned short* __restrict__ rl,
    const int* __restrict__ mask, float* __restrict__ outp, float* __restrict__ attnp) {
  __shared__ float Tlds[96 * 34];
  __shared__ unsigned int Plds[2048];     // [0,4096)B hi, [4096,8192)B lo ; rows of 128B
  __shared__ float mw[4][32], lw[4][32], mf[32], rlf[32];

  int tid = threadIdx.x;
  int w = tid >> 6, lane = tid & 63, li = lane & 15, g = lane >> 4;
  int q0 = blockIdx.x * 32;
  int bh = blockIdx.y, b = bh >> 3, h = bh & 7;
  const unsigned short* qAhp = qAh + (size_t)bh * 131072;
  const unsigned short* qAlp = qAl + (size_t)bh * 131072;
  const unsigned short* qBhp = qBh + (size_t)bh * 131072;
  const unsigned short* qBlp = qBl + (size_t)bh * 131072;
  const unsigned short* khhp = khh + (size_t)bh * 131072;
  const unsigned short* khlp = khl + (size_t)bh * 131072;
  const unsigned short* vThp = vTh + (size_t)bh * 131072;
  const unsigned short* vTlp = vTl + (size_t)bh * 131072;
  float* attn_bh = attnp + (size_t)bh * NL * NL;
  const int* mask_b = mask + (size_t)b * NL * NL;

  // Q fragments (B operands), resident for whole kernel
  bf16x8 fAh[2][2], fAl[2][2], fBh[2][2], fBl[2][2];
  #pragma unroll
  for (int nt = 0; nt < 2; ++nt)
    #pragma unroll
    for (int ks = 0; ks < 2; ++ks) {
      size_t o = (size_t)(q0 + 16 * nt + li) * 64 + 32 * ks + 8 * g;
      fAh[nt][ks] = *(const bf16x8*)(qAhp + o);
      fAl[nt][ks] = *(const bf16x8*)(qAlp + o);
      fBh[nt][ks] = *(const bf16x8*)(qBhp + o);
      fBl[nt][ks] = *(const bf16x8*)(qBlp + o);
    }
  float mrun[2] = {-3.0e38f, -3.0e38f}, lrun[2] = {0.f, 0.f};

  // ---------------- phase A ----------------
  for (int kt = 0; kt < 32; ++kt) {
    int k0 = kt * 64;
    int krow = k0 + 16 * w + li;
    f32x4 accS[2];
    #pragma unroll
    for (int i = 0; i < 2; ++i) { accS[i][0]=0.f; accS[i][1]=0.f; accS[i][2]=0.f; accS[i][3]=0.f; }
    #pragma unroll
    for (int ks = 0; ks < 2; ++ks) {
      size_t o = (size_t)krow * 64 + 32 * ks + 8 * g;
      bf16x8 ah = *(const bf16x8*)(khhp + o);
      bf16x8 al = *(const bf16x8*)(khlp + o);
      #pragma unroll
      for (int nt = 0; nt < 2; ++nt) {
        accS[nt] = MFMA(ah, fAh[nt][ks], accS[nt]);
        accS[nt] = MFMA(al, fAh[nt][ks], accS[nt]);
        accS[nt] = MFMA(ah, fAl[nt][ks], accS[nt]);
      }
    }
    int nlo = k0 - q0 + 2017;
    f32x4 accT[3];
    #pragma unroll
    for (int i = 0; i < 3; ++i) { accT[i][0]=0.f; accT[i][1]=0.f; accT[i][2]=0.f; accT[i][3]=0.f; }
    #pragma unroll
    for (int p = 0; p < 3; ++p) {
      int pi = w * 3 + p, jt = pi >> 1, ntp = pi & 1;
      int rrow = nlo + jt * 16 + li;
      if (rrow > 4095) rrow = 4095;
      #pragma unroll
      for (int ks = 0; ks < 2; ++ks) {
        size_t o = (size_t)rrow * 64 + 32 * ks + 8 * g;
        bf16x8 ah = *(const bf16x8*)(rh + o);
        bf16x8 al = *(const bf16x8*)(rl + o);
        accT[p] = MFMA(ah, fBh[ntp][ks], accT[p]);
        accT[p] = MFMA(al, fBh[ntp][ks], accT[p]);
        accT[p] = MFMA(ah, fBl[ntp][ks], accT[p]);
      }
    }
    __syncthreads();
    #pragma unroll
    for (int p = 0; p < 3; ++p) {
      int pi = w * 3 + p, jt = pi >> 1, ntp = pi & 1;
      #pragma unroll
      for (int r = 0; r < 4; ++r)
        Tlds[(jt * 16 + 4 * g + r) * 34 + ntp * 16 + li] = accT[p][r];
    }
    __syncthreads();
    #pragma unroll
    for (int nt = 0; nt < 2; ++nt) {
      int ql_ = 16 * nt + li;
      int qg = q0 + ql_;
      int kb = k0 + 16 * w + 4 * g;
      int4 mv = *(const int4*)(mask_b + (size_t)qg * NL + kb);
      float sv[4];
      #pragma unroll
      for (int r = 0; r < 4; ++r) {
        int kl = 16 * w + 4 * g + r;
        sv[r] = (accS[nt][r] + Tlds[(kl - ql_ + 31) * 34 + ql_]) * 0.125f;
      }
      if (mv.x == 0) sv[0] = -1e30f;
      if (mv.y == 0) sv[1] = -1e30f;
      if (mv.z == 0) sv[2] = -1e30f;
      if (mv.w == 0) sv[3] = -1e30f;
      *(float4*)(attn_bh + (size_t)qg * NL + kb) = make_float4(sv[0], sv[1], sv[2], sv[3]);
      float vmax = fmaxf(fmaxf(sv[0], sv[1]), fmaxf(sv[2], sv[3]));
      vmax = fmaxf(vmax, __shfl_xor(vmax, 16));
      vmax = fmaxf(vmax, __shfl_xor(vmax, 32));
      float sum = __expf(sv[0] - vmax) + __expf(sv[1] - vmax) +
                  __expf(sv[2] - vmax) + __expf(sv[3] - vmax);
      sum += __shfl_xor(sum, 16);
      sum += __shfl_xor(sum, 32);
      float mo = mrun[nt];
      float mn = fmaxf(mo, vmax);
      lrun[nt] = lrun[nt] * __expf(mo - mn) + sum * __expf(vmax - mn);
      mrun[nt] = mn;
    }
  }
  if (lane < 16) {
    mw[w][li] = mrun[0]; lw[w][li] = lrun[0];
    mw[w][16 + li] = mrun[1]; lw[w][16 + li] = lrun[1];
  }
  __syncthreads();
  if (tid < 32) {
    float m = mw[0][tid];
    m = fmaxf(m, mw[1][tid]); m = fmaxf(m, mw[2][tid]); m = fmaxf(m, mw[3][tid]);
    float l = lw[0][tid] * __expf(mw[0][tid] - m) + lw[1][tid] * __expf(mw[1][tid] - m) +
              lw[2][tid] * __expf(mw[2][tid] - m) + lw[3][tid] * __expf(mw[3][tid] - m);
    mf[tid] = m; rlf[tid] = 1.0f / l;
  }
  __syncthreads();

  // ---------------- phase B ----------------
  f32x4 accO[2];
  #pragma unroll
  for (int i = 0; i < 2; ++i) { accO[i][0]=0.f; accO[i][1]=0.f; accO[i][2]=0.f; accO[i][3]=0.f; }
  int qlc = tid >> 3;
  int kc = (tid & 7) * 8;
  float mm = mf[qlc], rr = rlf[qlc];
  unsigned int woff = (unsigned)(qlc * 128 + ((kc * 2) ^ ((qlc & 7) << 4)));

  for (int kt = 0; kt < 32; ++kt) {
    int k0 = kt * 64;
    float* pp = attn_bh + (size_t)(q0 + qlc) * NL + k0 + kc;
    float4 sa = *(float4*)pp;
    float4 sb = *(float4*)(pp + 4);
    float p0 = __expf(sa.x - mm) * rr, p1 = __expf(sa.y - mm) * rr;
    float p2 = __expf(sa.z - mm) * rr, p3 = __expf(sa.w - mm) * rr;
    float p4 = __expf(sb.x - mm) * rr, p5 = __expf(sb.y - mm) * rr;
    float p6 = __expf(sb.z - mm) * rr, p7 = __expf(sb.w - mm) * rr;
    *(float4*)pp = make_float4(p0, p1, p2, p3);
    *(float4*)(pp + 4) = make_float4(p4, p5, p6, p7);
    unsigned short h0 = bf16_rne(p0), h1 = bf16_rne(p1), h2 = bf16_rne(p2), h3 = bf16_rne(p3);
    unsigned short h4 = bf16_rne(p4), h5 = bf16_rne(p5), h6 = bf16_rne(p6), h7 = bf16_rne(p7);
    unsigned short e0 = bf16_rne(p0 - bf16_to_f(h0)), e1 = bf16_rne(p1 - bf16_to_f(h1));
    unsigned short e2 = bf16_rne(p2 - bf16_to_f(h2)), e3 = bf16_rne(p3 - bf16_to_f(h3));
    unsigned short e4 = bf16_rne(p4 - bf16_to_f(h4)), e5 = bf16_rne(p5 - bf16_to_f(h5));
    unsigned short e6 = bf16_rne(p6 - bf16_to_f(h6)), e7 = bf16_rne(p7 - bf16_to_f(h7));
    __syncthreads();
    *(uint4*)((char*)Plds + woff) =
        make_uint4((unsigned)h0 | ((unsigned)h1 << 16), (unsigned)h2 | ((unsigned)h3 << 16),
                   (unsigned)h4 | ((unsigned)h5 << 16), (unsigned)h6 | ((unsigned)h7 << 16));
    *(uint4*)((char*)Plds + 4096 + woff) =
        make_uint4((unsigned)e0 | ((unsigned)e1 << 16), (unsigned)e2 | ((unsigned)e3 << 16),
                   (unsigned)e4 | ((unsigned)e5 << 16), (unsigned)e6 | ((unsigned)e7 << 16));
    __syncthreads();
    #pragma unroll
    for (int ks = 0; ks < 2; ++ks) {
      size_t vo = (size_t)(16 * w + li) * NL + k0 + 32 * ks + 8 * g;
      bf16x8 vh_ = *(const bf16x8*)(vThp + vo);
      bf16x8 vl_ = *(const bf16x8*)(vTlp + vo);
      #pragma unroll
      for (int nt = 0; nt < 2; ++nt) {
        unsigned int ro = (unsigned)((16 * nt + li) * 128 + (((32 * ks + 8 * g) * 2) ^ ((li & 7) << 4)));
        bf16x8 ph = *(const bf16x8*)((const char*)Plds + ro);
        bf16x8 pl = *(const bf16x8*)((const char*)Plds + 4096 + ro);
        accO[nt] = MFMA(vh_, ph, accO[nt]);
        accO[nt] = MFMA(vl_, ph, accO[nt]);
        accO[nt] = MFMA(vh_, pl, accO[nt]);
      }
    }
  }
  #pragma unroll
  for (int nt = 0; nt < 2; ++nt) {
    int qg = q0 + 16 * nt + li;
    int d = 16 * w + 4 * g;
    *(float4*)(outp + ((size_t)b * NL + qg) * 512 + h * 64 + d) =
        make_float4(accO[nt][0], accO[nt][1], accO[nt][2], accO[nt][3]);
  }
}

// ============================================================
extern "C" void kernel_launch(void* const* d_in, const int* in_sizes, int n_in,
                              void* d_out, int out_size, void* d_ws, size_t ws_size,
                              hipStream_t stream) {
  const float* q    = (const float*)d_in[0];
  const float* k    = (const float*)d_in[1];
  const int*   mask = (const int*)d_in[2];
  const float* Wq   = (const float*)d_in[3];
  const float* Wkv  = (const float*)d_in[4];
  const float* Wr   = (const float*)d_in[5];
  const float* rrb  = (const float*)d_in[6];
  const float* rwb  = (const float*)d_in[7];

  float* outp  = (float*)d_out;                 // [2,2048,512]
  float* attnp = outp + (size_t)2 * NL * 512;   // [2,8,2048,2048]

  unsigned short* W = (unsigned short*)d_ws;
  // element offsets (all 16B-aligned)
  const size_t RHI = 0,            RLO = RHI + 262144;
  const size_t QSH = RLO + 262144, QSL = QSH + 2097152;
  const size_t KSH = QSL + 2097152, KSL = KSH + 2097152;
  const size_t WQH = KSL + 2097152, WQL = WQH + 262144;
  const size_t WKH = WQL + 262144,  WKL = WKH + 524288;
  const size_t QAH = WKL + 524288,  QAL = QAH + 2097152;
  const size_t QBH = QAL + 2097152, QBL = QBH + 2097152;
  const size_t KHH = QBL + 2097152, KHL = KHH + 2097152;
  const size_t VTH = KHL + 2097152, VTL = VTH + 2097152;

  hipLaunchKernelGGL(split_kernel, dim3(1024), dim3(256), 0, stream,
                     q, k, Wq, Wkv, W+QSH, W+QSL, W+KSH, W+KSL, W+WQH, W+WQL, W+WKH, W+WKL);
  hipLaunchKernelGGL(build_r_kernel, dim3(N2L), dim3(64), 0, stream, Wr, W+RHI, W+RLO);
  hipLaunchKernelGGL(proj_kernel, dim3(64, 24), dim3(256), 0, stream,
                     W+QSH, W+QSL, W+KSH, W+KSL, W+WQH, W+WQL, W+WKH, W+WKL, rrb, rwb,
                     W+QAH, W+QAL, W+QBH, W+QBL, W+KHH, W+KHL, W+VTH, W+VTL);
  hipLaunchKernelGGL(attn_kernel, dim3(64, 16), dim3(256), 0, stream,
                     W+QAH, W+QAL, W+QBH, W+QBL, W+KHH, W+KHL, W+VTH, W+VTL,
                     W+RHI, W+RLO, mask, outp, attnp);
}